// Round 16
// baseline (246.960 us; speedup 1.0000x reference)
//
#include <hip/hip_runtime.h>
#include <hip/hip_bf16.h>

#define N_NODES 100000
#define M_PAD   100096            // 782 * 128, padded row count for MFMA GEMM
#define N_EDGES 1600000
#define E_TOT   (N_EDGES + N_NODES)   // + self loops
#define NEG_SLOPE 0.2f

#define G_NODES 128                                  // nodes per bucket (pow2)
#define BUCKETS ((N_NODES + G_NODES - 1) / G_NODES)  // 782
#define REP 512                                      // slices
#define SLICE ((E_TOT + REP - 1) / REP)              // 3321 edges per slice
#define GB1 (M_PAD / 128)                            // 782 gemm blocks
#define CVTW_ELEMS (128 * 128 + 128 * 160)
#define CVTW_BLOCKS ((CVTW_ELEMS + 255) / 256)

typedef __attribute__((ext_vector_type(8))) short s16x8;
typedef __attribute__((ext_vector_type(4))) float f32x4;
typedef __attribute__((ext_vector_type(2))) float f32x2;

__device__ __forceinline__ float lo16(unsigned u) { return __uint_as_float(u << 16); }
__device__ __forceinline__ float hi16(unsigned u) { return __uint_as_float(u & 0xffff0000u); }

__device__ __forceinline__ short f2bf(float f) {
    __hip_bfloat16 b = __float2bfloat16(f);
    return *(short*)&b;
}

// ================= CSR build bodies =================

__device__ void slice_count_body(const int* __restrict__ ei, int* __restrict__ cnt, int r) {
    __shared__ int h[BUCKETS];
    for (int i = threadIdx.x; i < BUCKETS; i += 256) h[i] = 0;
    __syncthreads();
    int lo = r * SLICE, hi = min(lo + SLICE, E_TOT);
    for (int e = lo + threadIdx.x; e < hi; e += 256) {
        int d = (e < N_EDGES) ? ei[N_EDGES + e] : e - N_EDGES;
        atomicAdd(&h[d >> 7], 1);
    }
    __syncthreads();
    for (int i = threadIdx.x; i < BUCKETS; i += 256)
        cnt[(size_t)r * BUCKETS + i] = h[i];
}

// 256 threads, 2 slice-rows per thread: exclusive scan down bucket b's column
__device__ void col_scan256_body(int* __restrict__ cnt, int* __restrict__ bsum, int b) {
    __shared__ int lds[256];
    int tid = threadIdx.x;
    int v0 = cnt[(size_t)(2 * tid) * BUCKETS + b];
    int v1 = cnt[(size_t)(2 * tid + 1) * BUCKETS + b];
    int s = v0 + v1;
    lds[tid] = s;
    __syncthreads();
    for (int off = 1; off < 256; off <<= 1) {
        int t = (tid >= off) ? lds[tid - off] : 0;
        __syncthreads();
        lds[tid] += t;
        __syncthreads();
    }
    int excl = lds[tid] - s;
    cnt[(size_t)(2 * tid) * BUCKETS + b]     = excl;
    cnt[(size_t)(2 * tid + 1) * BUCKETS + b] = excl + v0;
    if (tid == 255) bsum[b] = lds[255];
}

__global__ __launch_bounds__(1024) void bucket_scan_kernel(const int* __restrict__ bsum,
                                                           int* __restrict__ boff) {
    __shared__ int lds[1024];
    int tid = threadIdx.x;
    int v = (tid < BUCKETS) ? bsum[tid] : 0;
    lds[tid] = v;
    __syncthreads();
    for (int off = 1; off < 1024; off <<= 1) {
        int t = (tid >= off) ? lds[tid - off] : 0;
        __syncthreads();
        lds[tid] += t;
        __syncthreads();
    }
    if (tid < BUCKETS) boff[tid] = lds[tid] - v;
    if (tid == 0) boff[BUCKETS] = E_TOT;
}

__global__ __launch_bounds__(256) void bucket_scatter_kernel(const int* __restrict__ ei,
                                                             const int* __restrict__ colx,
                                                             const int* __restrict__ boff,
                                                             int* __restrict__ tmp) {
    __shared__ int lcur[BUCKETS];
    int r = blockIdx.x;
    for (int i = threadIdx.x; i < BUCKETS; i += 256)
        lcur[i] = boff[i] + colx[(size_t)r * BUCKETS + i];
    __syncthreads();
    int lo = r * SLICE, hi = min(lo + SLICE, E_TOT);
    for (int e = lo + threadIdx.x; e < hi; e += 256) {
        int s, d;
        if (e < N_EDGES) { s = ei[e]; d = ei[N_EDGES + e]; }
        else             { s = d = e - N_EDGES; }
        int pos = atomicAdd(&lcur[d >> 7], 1);
        tmp[pos] = (s << 7) | (d & (G_NODES - 1));
    }
}

__global__ __launch_bounds__(256) void bucket_build_kernel(const int* __restrict__ tmp,
                                                           const int* __restrict__ boff,
                                                           int* __restrict__ rowptr,
                                                           int* __restrict__ csr) {
    __shared__ int hcnt[G_NODES];
    __shared__ int hoff[G_NODES];
    int b = blockIdx.x;
    int base = boff[b], cnt = boff[b + 1] - base;
    int tid = threadIdx.x;
    if (tid < G_NODES) hcnt[tid] = 0;
    __syncthreads();
    for (int i = tid; i < cnt; i += 256)
        atomicAdd(&hcnt[tmp[base + i] & (G_NODES - 1)], 1);
    __syncthreads();
    if (tid < G_NODES) hoff[tid] = hcnt[tid];
    __syncthreads();
    for (int off = 1; off < G_NODES; off <<= 1) {
        int t = (tid < G_NODES && tid >= off) ? hoff[tid - off] : 0;
        __syncthreads();
        if (tid < G_NODES) hoff[tid] += t;
        __syncthreads();
    }
    if (tid < G_NODES) {
        int excl = hoff[tid] - hcnt[tid];
        int node = b * G_NODES + tid;
        if (node < N_NODES) rowptr[node] = base + excl;
        hcnt[tid] = excl;       // reuse as cursor
    }
    __syncthreads();
    for (int i = tid; i < cnt; i += 256) {
        int v = tmp[base + i];
        int pos = base + atomicAdd(&hcnt[v & (G_NODES - 1)], 1);
        csr[pos] = v >> 7;
    }
    if (b == 0 && tid < 8) csr[E_TOT + tid] = 0;
    if (b == 0 && tid == 0) rowptr[N_NODES] = E_TOT;
}

// ================= weights =================

__device__ void cvt_w_body(const float* __restrict__ W1, __hip_bfloat16* __restrict__ W1t,
                           const float* __restrict__ W2, __hip_bfloat16* __restrict__ W2t,
                           int idx) {
    if (idx < 128 * 128) {
        int k = idx >> 7, n = idx & 127;
        W1t[n * 128 + k] = __float2bfloat16(W1[idx]);
    } else if (idx < CVTW_ELEMS) {
        int i = idx - 128 * 128;
        int k = i / 160, n = i - k * 160;
        W2t[n * 128 + k] = __float2bfloat16(W2[i]);
    }
}

// ================= fused GEMM + score epilogue =================

template<int NCOLS>
__device__ __forceinline__ void score_epilogue(const f32x4* acc, int rbase, int wc,
                                               int l15, int lk,
                                               const float* __restrict__ as,
                                               const float* __restrict__ ad,
                                               float* __restrict__ s_src,
                                               float* __restrict__ s_dst) {
    constexpr int CG = NCOLS / 32;
    constexpr int HEADW = NCOLS / 4;
    #pragma unroll
    for (int j = 0; j < 4; ++j) {
        float pa = 0.f, pb = 0.f, qa = 0.f, qb = 0.f;
        #pragma unroll
        for (int cg = 0; cg < CG; ++cg) {
            int c = wc * (NCOLS / 2) + cg * 16 + l15;
            float v = acc[cg][j];
            float ws = as[c], wd = ad[c];
            if (c >= (wc * 2 + 1) * HEADW) { pb += v * ws; qb += v * wd; }
            else                           { pa += v * ws; qa += v * wd; }
        }
        #pragma unroll
        for (int off = 1; off < 16; off <<= 1) {
            pa += __shfl_xor(pa, off); pb += __shfl_xor(pb, off);
            qa += __shfl_xor(qa, off); qb += __shfl_xor(qb, off);
        }
        int row = rbase + lk * 4 + j;
        if (l15 == 0 && row < N_NODES) {
            int ha = wc * 2;
            s_src[row * 4 + ha]     = pa;
            s_src[row * 4 + ha + 1] = pb;
            s_dst[row * 4 + ha]     = qa;
            s_dst[row * 4 + ha + 1] = qb;
        }
    }
}

// layer-1 GEMM: A f32 converted in-register, output fp8 + scores
__device__ void gemm1_body(const float* __restrict__ A, const __hip_bfloat16* __restrict__ Bt,
                           unsigned char* __restrict__ Cq,
                           const float* __restrict__ as, const float* __restrict__ ad,
                           float* __restrict__ s_src, float* __restrict__ s_dst, int bid) {
    constexpr int NCOLS = 128;
    constexpr int CG = NCOLS / 32;
    int wid = threadIdx.x >> 6;
    int lane = threadIdx.x & 63;
    int wr = wid >> 1, wc = wid & 1;
    int l15 = lane & 15, lk = lane >> 4;

    s16x8 bfrag[CG][4];
    #pragma unroll
    for (int cg = 0; cg < CG; ++cg) {
        int col = wc * (NCOLS / 2) + cg * 16 + l15;
        #pragma unroll
        for (int ks = 0; ks < 4; ++ks)
            bfrag[cg][ks] = *(const s16x8*)&Bt[col * 128 + ks * 32 + lk * 8];
    }
    int rowblk = bid * 128;
    #pragma unroll
    for (int st = 0; st < 4; ++st) {
        int rbase = rowblk + st * 32 + wr * 16;
        int row = rbase + l15;
        bool ok = row < N_NODES;
        s16x8 afrag[4];
        #pragma unroll
        for (int ks = 0; ks < 4; ++ks) {
            if (ok) {
                float4 a0 = *(const float4*)&A[(size_t)row * 128 + ks * 32 + lk * 8];
                float4 a1 = *(const float4*)&A[(size_t)row * 128 + ks * 32 + lk * 8 + 4];
                s16x8 af;
                af[0] = f2bf(a0.x); af[1] = f2bf(a0.y); af[2] = f2bf(a0.z); af[3] = f2bf(a0.w);
                af[4] = f2bf(a1.x); af[5] = f2bf(a1.y); af[6] = f2bf(a1.z); af[7] = f2bf(a1.w);
                afrag[ks] = af;
            } else {
                afrag[ks] = (s16x8){0,0,0,0,0,0,0,0};
            }
        }
        f32x4 acc[CG];
        #pragma unroll
        for (int cg = 0; cg < CG; ++cg) acc[cg] = (f32x4){0.f, 0.f, 0.f, 0.f};
        #pragma unroll
        for (int ks = 0; ks < 4; ++ks) {
            #pragma unroll
            for (int cg = 0; cg < CG; ++cg)
                acc[cg] = __builtin_amdgcn_mfma_f32_16x16x32_bf16(afrag[ks], bfrag[cg][ks], acc[cg], 0, 0, 0);
        }
        #pragma unroll
        for (int cg = 0; cg < CG; ++cg) {
            int c = wc * (NCOLS / 2) + cg * 16 + l15;
            unsigned w01 = __builtin_amdgcn_cvt_pk_fp8_f32(acc[cg][0], acc[cg][1], 0, false);
            unsigned w23 = __builtin_amdgcn_cvt_pk_fp8_f32(acc[cg][2], acc[cg][3], 0, false);
            size_t base = (size_t)(rbase + lk * 4) * NCOLS + c;
            Cq[base]             = (unsigned char)(w01 & 0xff);
            Cq[base + NCOLS]     = (unsigned char)((w01 >> 8) & 0xff);
            Cq[base + 2 * NCOLS] = (unsigned char)(w23 & 0xff);
            Cq[base + 3 * NCOLS] = (unsigned char)((w23 >> 8) & 0xff);
        }
        score_epilogue<NCOLS>(acc, rbase, wc, l15, lk, as, ad, s_src, s_dst);
    }
}

// layer-2 GEMM: bf16 A, output fp8 + scores
template<int NCOLS>
__global__ __launch_bounds__(256) void mfma_gemm_score_kernel(const __hip_bfloat16* __restrict__ A,
                                                              const __hip_bfloat16* __restrict__ Bt,
                                                              unsigned char* __restrict__ Cq,
                                                              const float* __restrict__ as,
                                                              const float* __restrict__ ad,
                                                              float* __restrict__ s_src,
                                                              float* __restrict__ s_dst) {
    constexpr int CG = NCOLS / 32;
    int wid = threadIdx.x >> 6;
    int lane = threadIdx.x & 63;
    int wr = wid >> 1, wc = wid & 1;
    int l15 = lane & 15, lk = lane >> 4;

    s16x8 bfrag[CG][4];
    #pragma unroll
    for (int cg = 0; cg < CG; ++cg) {
        int col = wc * (NCOLS / 2) + cg * 16 + l15;
        #pragma unroll
        for (int ks = 0; ks < 4; ++ks)
            bfrag[cg][ks] = *(const s16x8*)&Bt[col * 128 + ks * 32 + lk * 8];
    }
    int rowblk = blockIdx.x * 128;
    #pragma unroll
    for (int st = 0; st < 4; ++st) {
        int rbase = rowblk + st * 32 + wr * 16;
        s16x8 afrag[4];
        #pragma unroll
        for (int ks = 0; ks < 4; ++ks)
            afrag[ks] = *(const s16x8*)&A[(size_t)(rbase + l15) * 128 + ks * 32 + lk * 8];
        f32x4 acc[CG];
        #pragma unroll
        for (int cg = 0; cg < CG; ++cg) acc[cg] = (f32x4){0.f, 0.f, 0.f, 0.f};
        #pragma unroll
        for (int ks = 0; ks < 4; ++ks) {
            #pragma unroll
            for (int cg = 0; cg < CG; ++cg)
                acc[cg] = __builtin_amdgcn_mfma_f32_16x16x32_bf16(afrag[ks], bfrag[cg][ks], acc[cg], 0, 0, 0);
        }
        #pragma unroll
        for (int cg = 0; cg < CG; ++cg) {
            int c = wc * (NCOLS / 2) + cg * 16 + l15;
            unsigned w01 = __builtin_amdgcn_cvt_pk_fp8_f32(acc[cg][0], acc[cg][1], 0, false);
            unsigned w23 = __builtin_amdgcn_cvt_pk_fp8_f32(acc[cg][2], acc[cg][3], 0, false);
            size_t base = (size_t)(rbase + lk * 4) * NCOLS + c;
            Cq[base]             = (unsigned char)(w01 & 0xff);
            Cq[base + NCOLS]     = (unsigned char)((w01 >> 8) & 0xff);
            Cq[base + 2 * NCOLS] = (unsigned char)(w23 & 0xff);
            Cq[base + 3 * NCOLS] = (unsigned char)((w23 >> 8) & 0xff);
        }
        score_epilogue<NCOLS>(acc, rbase, wc, l15, lk, as, ad, s_src, s_dst);
    }
}

// ================= mega kernels =================

__global__ __launch_bounds__(256) void k0_slice_cvtw(const int* __restrict__ ei,
                                                     int* __restrict__ cnt,
                                                     const float* __restrict__ W1,
                                                     __hip_bfloat16* __restrict__ W1t,
                                                     const float* __restrict__ W2,
                                                     __hip_bfloat16* __restrict__ W2t) {
    if (blockIdx.x < REP) { slice_count_body(ei, cnt, blockIdx.x); return; }
    cvt_w_body(W1, W1t, W2, W2t, (blockIdx.x - REP) * 256 + threadIdx.x);
}

__global__ __launch_bounds__(256) void k1_colscan_gemm1(int* __restrict__ cnt,
                                                        int* __restrict__ bsum,
                                                        const float* __restrict__ A,
                                                        const __hip_bfloat16* __restrict__ Bt,
                                                        unsigned char* __restrict__ Cq,
                                                        const float* __restrict__ as1,
                                                        const float* __restrict__ ad1,
                                                        float* __restrict__ s_src1,
                                                        float* __restrict__ s_dst1) {
    if (blockIdx.x < BUCKETS) { col_scan256_body(cnt, bsum, blockIdx.x); return; }
    gemm1_body(A, Bt, Cq, as1, ad1, s_src1, s_dst1, blockIdx.x - BUCKETS);
}

// ================= aggregation (round-11 structure + main/tail split) =================

__global__ __launch_bounds__(256) void agg1_kernel(
        const unsigned char* __restrict__ h1q, const float* __restrict__ s_src,
        const float* __restrict__ s_dst, const int* __restrict__ rowptr,
        const int* __restrict__ csr, const float* __restrict__ b1,
        __hip_bfloat16* __restrict__ out1) {
    int d = blockIdx.x * 4 + (threadIdx.x >> 6);
    if (d >= N_NODES) return;
    int lane = threadIdx.x & 63;
    int c0 = lane * 2;
    int hd = lane >> 4;
    int bp = hd << 2;                                  // bpermute byte base
    int eg = (lane >> 2) & 7;                          // edge slot this lane scores
    float sdall = s_dst[d * 4 + (lane & 3)];
    f32x2 acc = {0.f, 0.f};
    float z = 0.f;
    int beg = __builtin_amdgcn_readfirstlane(rowptr[d]);
    int end = __builtin_amdgcn_readfirstlane(rowptr[d + 1]);
    int jfull = beg + ((end - beg) & ~7);
    int j = beg;
    for (; j < jfull; j += 8) {                        // full groups: no clamps
        int se = csr[j + eg];
        float ee = s_src[(size_t)se * 4 + (lane & 3)] + sdall;
        ee = fmaxf(ee, NEG_SLOPE * ee);
        float qv = __expf(ee);
        int qbits = __float_as_int(qv);
        #pragma unroll
        for (int t = 0; t < 8; ++t) {
            float q = __int_as_float(__builtin_amdgcn_ds_bpermute(bp + t * 16, qbits));
            int s = __builtin_amdgcn_readfirstlane(csr[j + t]);
            unsigned u = *(const unsigned short*)&h1q[(size_t)s * 128 + c0];
            f32x2 v = __builtin_amdgcn_cvt_pk_f32_fp8(u, false);
            f32x2 qq = {q, q};
            acc += qq * v;
            z += q;
        }
    }
    if (j < end) {                                     // tail group: uniform per-slot guards
        int cnt = end - j;
        int se = csr[min(j + eg, end - 1)];
        float ee = s_src[(size_t)se * 4 + (lane & 3)] + sdall;
        ee = fmaxf(ee, NEG_SLOPE * ee);
        float qv = (eg < cnt) ? __expf(ee) : 0.f;
        int qbits = __float_as_int(qv);
        #pragma unroll
        for (int t = 0; t < 8; ++t) {
            if (j + t < end) {
                float q = __int_as_float(__builtin_amdgcn_ds_bpermute(bp + t * 16, qbits));
                int s = __builtin_amdgcn_readfirstlane(csr[j + t]);
                unsigned u = *(const unsigned short*)&h1q[(size_t)s * 128 + c0];
                f32x2 v = __builtin_amdgcn_cvt_pk_f32_fp8(u, false);
                f32x2 qq = {q, q};
                acc += qq * v;
                z += q;
            }
        }
    }
    float invz = 1.0f / z;
    float vx = acc.x * invz + b1[c0];
    float vy = acc.y * invz + b1[c0 + 1];
    vx = vx > 0.f ? vx : __expf(vx) - 1.0f;   // ELU
    vy = vy > 0.f ? vy : __expf(vy) - 1.0f;
    __hip_bfloat162 o;
    o.x = __float2bfloat16(vx);
    o.y = __float2bfloat16(vy);
    *(__hip_bfloat162*)&out1[(size_t)d * 128 + c0] = o;
}

__global__ __launch_bounds__(256) void agg2_kernel(
        const unsigned char* __restrict__ h2q, const float* __restrict__ s_src,
        const float* __restrict__ s_dst, const int* __restrict__ rowptr,
        const int* __restrict__ csr, const float* __restrict__ b2,
        float* __restrict__ out) {
    int d = blockIdx.x * 4 + (threadIdx.x >> 6);
    if (d >= N_NODES) return;
    int lane = threadIdx.x & 63;
    int ll = lane < 40 ? lane : 39;
    int hd = ll / 10;
    int bp = hd << 2;
    int eg = (lane >> 2) & 7;
    int voff = ll * 4;                         // byte offset within 160-B row
    float sdall = s_dst[d * 4 + (lane & 3)];
    f32x2 acc01 = {0.f, 0.f}, acc23 = {0.f, 0.f};
    float z = 0.f;
    int beg = __builtin_amdgcn_readfirstlane(rowptr[d]);
    int end = __builtin_amdgcn_readfirstlane(rowptr[d + 1]);
    int jfull = beg + ((end - beg) & ~7);
    int j = beg;
    for (; j < jfull; j += 8) {                        // full groups: no clamps
        int se = csr[j + eg];
        float ee = s_src[(size_t)se * 4 + (lane & 3)] + sdall;
        ee = fmaxf(ee, NEG_SLOPE * ee);
        float qv = __expf(ee);
        int qbits = __float_as_int(qv);
        #pragma unroll
        for (int t = 0; t < 8; ++t) {
            float q = __int_as_float(__builtin_amdgcn_ds_bpermute(bp + t * 16, qbits));
            int s = __builtin_amdgcn_readfirstlane(csr[j + t]);
            unsigned u = *(const unsigned*)&h2q[(size_t)s * 160 + voff];
            f32x2 v01 = __builtin_amdgcn_cvt_pk_f32_fp8(u, false);
            f32x2 v23 = __builtin_amdgcn_cvt_pk_f32_fp8(u, true);
            f32x2 qq = {q, q};
            acc01 += qq * v01;
            acc23 += qq * v23;
            z += q;
        }
    }
    if (j < end) {                                     // tail group: uniform per-slot guards
        int cnt = end - j;
        int se = csr[min(j + eg, end - 1)];
        float ee = s_src[(size_t)se * 4 + (lane & 3)] + sdall;
        ee = fmaxf(ee, NEG_SLOPE * ee);
        float qv = (eg < cnt) ? __expf(ee) : 0.f;
        int qbits = __float_as_int(qv);
        #pragma unroll
        for (int t = 0; t < 8; ++t) {
            if (j + t < end) {
                float q = __int_as_float(__builtin_amdgcn_ds_bpermute(bp + t * 16, qbits));
                int s = __builtin_amdgcn_readfirstlane(csr[j + t]);
                unsigned u = *(const unsigned*)&h2q[(size_t)s * 160 + voff];
                f32x2 v01 = __builtin_amdgcn_cvt_pk_f32_fp8(u, false);
                f32x2 v23 = __builtin_amdgcn_cvt_pk_f32_fp8(u, true);
                f32x2 qq = {q, q};
                acc01 += qq * v01;
                acc23 += qq * v23;
                z += q;
            }
        }
    }
    float invz = 1.0f / z;
    float rx = acc01.x * invz, ry = acc01.y * invz;
    float rz = acc23.x * invz, rw = acc23.y * invz;
    float sx = rx + __shfl(rx, lane + 10) + __shfl(rx, lane + 20) + __shfl(rx, lane + 30);
    float sy = ry + __shfl(ry, lane + 10) + __shfl(ry, lane + 20) + __shfl(ry, lane + 30);
    float sz = rz + __shfl(rz, lane + 10) + __shfl(rz, lane + 20) + __shfl(rz, lane + 30);
    float sw = rw + __shfl(rw, lane + 10) + __shfl(rw, lane + 20) + __shfl(rw, lane + 30);
    int lc = lane < 10 ? lane : 9;
    float4 bb = *(const float4*)&b2[lc * 4];
    bool own = lane < 10;
    float vx = own ? sx * 0.25f + bb.x : -1e30f;
    float vy = own ? sy * 0.25f + bb.y : -1e30f;
    float vz = own ? sz * 0.25f + bb.z : -1e30f;
    float vw = own ? sw * 0.25f + bb.w : -1e30f;
    float m = fmaxf(fmaxf(vx, vy), fmaxf(vz, vw));
    #pragma unroll
    for (int off = 1; off < 16; off <<= 1) m = fmaxf(m, __shfl_xor(m, off));
    float ssum = 0.f;
    if (own) {
        ssum = __expf(vx - m) + __expf(vy - m) + __expf(vz - m) + __expf(vw - m);
    }
    #pragma unroll
    for (int off = 1; off < 16; off <<= 1) ssum += __shfl_xor(ssum, off);
    float lse = m + __logf(ssum);
    if (own) {
        float4 o = {vx - lse, vy - lse, vz - lse, vw - lse};
        *(float4*)&out[(size_t)d * 40 + lane * 4] = o;
    }
}

// ================= launch =================

extern "C" void kernel_launch(void* const* d_in, const int* in_sizes, int n_in,
                              void* d_out, int out_size, void* d_ws, size_t ws_size,
                              hipStream_t stream) {
    const float* x   = (const float*)d_in[0];
    const int*   ei  = (const int*)d_in[1];
    const float* W1  = (const float*)d_in[2];
    const float* as1 = (const float*)d_in[3];
    const float* ad1 = (const float*)d_in[4];
    const float* b1  = (const float*)d_in[5];
    const float* W2  = (const float*)d_in[6];
    const float* as2 = (const float*)d_in[7];
    const float* ad2 = (const float*)d_in[8];
    const float* b2  = (const float*)d_in[9];
    float* out = (float*)d_out;

    char* ws = (char*)d_ws;
    size_t off = 0;
    auto alloc = [&](size_t bytes) {
        void* p = ws + off;
        off += (bytes + 255) & ~(size_t)255;
        return p;
    };
    unsigned char*  h1q   = (unsigned char*)alloc((size_t)M_PAD * 128);
    unsigned char*  h2q   = (unsigned char*)alloc((size_t)M_PAD * 160);
    __hip_bfloat16* out1b = (__hip_bfloat16*)alloc((size_t)M_PAD * 128 * 2);
    __hip_bfloat16* W1t   = (__hip_bfloat16*)alloc((size_t)128 * 128 * 2);
    __hip_bfloat16* W2t   = (__hip_bfloat16*)alloc((size_t)160 * 128 * 2);
    float* s_src1  = (float*)alloc((size_t)N_NODES * 4 * 4);
    float* s_dst1  = (float*)alloc((size_t)N_NODES * 4 * 4);
    float* s_src2  = (float*)alloc((size_t)N_NODES * 4 * 4);
    float* s_dst2  = (float*)alloc((size_t)N_NODES * 4 * 4);
    int*   tmp     = (int*)alloc((size_t)E_TOT * 4);
    int*   rowptr  = (int*)alloc((size_t)(N_NODES + 1) * 4);
    int*   csr     = (int*)alloc((size_t)(E_TOT + 8) * 4);   // +8 pad
    int*   cnt     = (int*)alloc((size_t)REP * BUCKETS * 4);
    int*   bsum    = (int*)alloc((size_t)BUCKETS * 4);
    int*   boff    = (int*)alloc((size_t)(BUCKETS + 1) * 4);

    // K0: slice-count (CSR) || weight conversion
    k0_slice_cvtw<<<REP + CVTW_BLOCKS, 256, 0, stream>>>(ei, cnt, W1, W1t, W2, W2t);
    // K1: column scan (CSR) || GEMM layer 1 (f32 x -> fp8 h1q) + fused score1
    k1_colscan_gemm1<<<BUCKETS + GB1, 256, 0, stream>>>(cnt, bsum, x, W1t, h1q,
                                                        as1, ad1, s_src1, s_dst1);
    // CSR finish
    bucket_scan_kernel<<<1, 1024, 0, stream>>>(bsum, boff);
    bucket_scatter_kernel<<<REP, 256, 0, stream>>>(ei, cnt, boff, tmp);
    bucket_build_kernel<<<BUCKETS, 256, 0, stream>>>(tmp, boff, rowptr, csr);

    // layer 1 aggregation
    agg1_kernel<<<(N_NODES + 3) / 4, 256, 0, stream>>>(h1q, s_src1, s_dst1, rowptr, csr, b1, out1b);

    // layer 2: GEMM + fused score2, then aggregation
    mfma_gemm_score_kernel<160><<<GB1, 256, 0, stream>>>(out1b, W2t, h2q,
                                                         as2, ad2, s_src2, s_dst2);
    agg2_kernel<<<(N_NODES + 3) / 4, 256, 0, stream>>>(h2q, s_src2, s_dst2, rowptr, csr, b2, out);
}

// Round 17
// 234.910 us; speedup vs baseline: 1.0513x; 1.0513x over previous
//
#include <hip/hip_runtime.h>
#include <hip/hip_bf16.h>

#define N_NODES 100000
#define M_PAD   100096            // 782 * 128, padded row count for MFMA GEMM
#define N_EDGES 1600000
#define E_TOT   (N_EDGES + N_NODES)   // + self loops
#define NEG_SLOPE 0.2f

#define G_NODES 128                                  // nodes per bucket (pow2)
#define BUCKETS ((N_NODES + G_NODES - 1) / G_NODES)  // 782
#define REP 512                                      // slices
#define SLICE ((E_TOT + REP - 1) / REP)              // 3321 edges per slice
#define GB1 (M_PAD / 128)                            // 782 gemm blocks
#define CVTW_ELEMS (128 * 128 + 128 * 160)
#define CVTW_BLOCKS ((CVTW_ELEMS + 255) / 256)

typedef __attribute__((ext_vector_type(8))) short s16x8;
typedef __attribute__((ext_vector_type(4))) float f32x4;
typedef __attribute__((ext_vector_type(2))) float f32x2;

__device__ __forceinline__ float lo16(unsigned u) { return __uint_as_float(u << 16); }
__device__ __forceinline__ float hi16(unsigned u) { return __uint_as_float(u & 0xffff0000u); }

__device__ __forceinline__ short f2bf(float f) {
    __hip_bfloat16 b = __float2bfloat16(f);
    return *(short*)&b;
}

// ================= CSR build bodies =================

__device__ void slice_count_body(const int* __restrict__ ei, int* __restrict__ cnt, int r) {
    __shared__ int h[BUCKETS];
    for (int i = threadIdx.x; i < BUCKETS; i += 256) h[i] = 0;
    __syncthreads();
    int lo = r * SLICE, hi = min(lo + SLICE, E_TOT);
    for (int e = lo + threadIdx.x; e < hi; e += 256) {
        int d = (e < N_EDGES) ? ei[N_EDGES + e] : e - N_EDGES;
        atomicAdd(&h[d >> 7], 1);
    }
    __syncthreads();
    for (int i = threadIdx.x; i < BUCKETS; i += 256)
        cnt[(size_t)r * BUCKETS + i] = h[i];
}

// 256 threads, 2 slice-rows per thread: exclusive scan down bucket b's column
__device__ void col_scan256_body(int* __restrict__ cnt, int* __restrict__ bsum, int b) {
    __shared__ int lds[256];
    int tid = threadIdx.x;
    int v0 = cnt[(size_t)(2 * tid) * BUCKETS + b];
    int v1 = cnt[(size_t)(2 * tid + 1) * BUCKETS + b];
    int s = v0 + v1;
    lds[tid] = s;
    __syncthreads();
    for (int off = 1; off < 256; off <<= 1) {
        int t = (tid >= off) ? lds[tid - off] : 0;
        __syncthreads();
        lds[tid] += t;
        __syncthreads();
    }
    int excl = lds[tid] - s;
    cnt[(size_t)(2 * tid) * BUCKETS + b]     = excl;
    cnt[(size_t)(2 * tid + 1) * BUCKETS + b] = excl + v0;
    if (tid == 255) bsum[b] = lds[255];
}

__global__ __launch_bounds__(1024) void bucket_scan_kernel(const int* __restrict__ bsum,
                                                           int* __restrict__ boff) {
    __shared__ int lds[1024];
    int tid = threadIdx.x;
    int v = (tid < BUCKETS) ? bsum[tid] : 0;
    lds[tid] = v;
    __syncthreads();
    for (int off = 1; off < 1024; off <<= 1) {
        int t = (tid >= off) ? lds[tid - off] : 0;
        __syncthreads();
        lds[tid] += t;
        __syncthreads();
    }
    if (tid < BUCKETS) boff[tid] = lds[tid] - v;
    if (tid == 0) boff[BUCKETS] = E_TOT;
}

__global__ __launch_bounds__(256) void bucket_scatter_kernel(const int* __restrict__ ei,
                                                             const int* __restrict__ colx,
                                                             const int* __restrict__ boff,
                                                             int* __restrict__ tmp) {
    __shared__ int lcur[BUCKETS];
    int r = blockIdx.x;
    for (int i = threadIdx.x; i < BUCKETS; i += 256)
        lcur[i] = boff[i] + colx[(size_t)r * BUCKETS + i];
    __syncthreads();
    int lo = r * SLICE, hi = min(lo + SLICE, E_TOT);
    for (int e = lo + threadIdx.x; e < hi; e += 256) {
        int s, d;
        if (e < N_EDGES) { s = ei[e]; d = ei[N_EDGES + e]; }
        else             { s = d = e - N_EDGES; }
        int pos = atomicAdd(&lcur[d >> 7], 1);
        tmp[pos] = (s << 7) | (d & (G_NODES - 1));
    }
}

__global__ __launch_bounds__(256) void bucket_build_kernel(const int* __restrict__ tmp,
                                                           const int* __restrict__ boff,
                                                           int* __restrict__ rowptr,
                                                           int* __restrict__ csr) {
    __shared__ int hcnt[G_NODES];
    __shared__ int hoff[G_NODES];
    int b = blockIdx.x;
    int base = boff[b], cnt = boff[b + 1] - base;
    int tid = threadIdx.x;
    if (tid < G_NODES) hcnt[tid] = 0;
    __syncthreads();
    for (int i = tid; i < cnt; i += 256)
        atomicAdd(&hcnt[tmp[base + i] & (G_NODES - 1)], 1);
    __syncthreads();
    if (tid < G_NODES) hoff[tid] = hcnt[tid];
    __syncthreads();
    for (int off = 1; off < G_NODES; off <<= 1) {
        int t = (tid < G_NODES && tid >= off) ? hoff[tid - off] : 0;
        __syncthreads();
        if (tid < G_NODES) hoff[tid] += t;
        __syncthreads();
    }
    if (tid < G_NODES) {
        int excl = hoff[tid] - hcnt[tid];
        int node = b * G_NODES + tid;
        if (node < N_NODES) rowptr[node] = base + excl;
        hcnt[tid] = excl;       // reuse as cursor
    }
    __syncthreads();
    for (int i = tid; i < cnt; i += 256) {
        int v = tmp[base + i];
        int pos = base + atomicAdd(&hcnt[v & (G_NODES - 1)], 1);
        csr[pos] = v >> 7;
    }
    if (b == 0 && tid < 8) csr[E_TOT + tid] = 0;
    if (b == 0 && tid == 0) rowptr[N_NODES] = E_TOT;
}

// ================= weights =================

__device__ void cvt_w_body(const float* __restrict__ W1, __hip_bfloat16* __restrict__ W1t,
                           const float* __restrict__ W2, __hip_bfloat16* __restrict__ W2t,
                           int idx) {
    if (idx < 128 * 128) {
        int k = idx >> 7, n = idx & 127;
        W1t[n * 128 + k] = __float2bfloat16(W1[idx]);
    } else if (idx < CVTW_ELEMS) {
        int i = idx - 128 * 128;
        int k = i / 160, n = i - k * 160;
        W2t[n * 128 + k] = __float2bfloat16(W2[i]);
    }
}

// ================= fused GEMM + score epilogue =================

template<int NCOLS>
__device__ __forceinline__ void score_epilogue(const f32x4* acc, int rbase, int wc,
                                               int l15, int lk,
                                               const float* __restrict__ as,
                                               const float* __restrict__ ad,
                                               float* __restrict__ s_src,
                                               float* __restrict__ s_dst) {
    constexpr int CG = NCOLS / 32;
    constexpr int HEADW = NCOLS / 4;
    #pragma unroll
    for (int j = 0; j < 4; ++j) {
        float pa = 0.f, pb = 0.f, qa = 0.f, qb = 0.f;
        #pragma unroll
        for (int cg = 0; cg < CG; ++cg) {
            int c = wc * (NCOLS / 2) + cg * 16 + l15;
            float v = acc[cg][j];
            float ws = as[c], wd = ad[c];
            if (c >= (wc * 2 + 1) * HEADW) { pb += v * ws; qb += v * wd; }
            else                           { pa += v * ws; qa += v * wd; }
        }
        #pragma unroll
        for (int off = 1; off < 16; off <<= 1) {
            pa += __shfl_xor(pa, off); pb += __shfl_xor(pb, off);
            qa += __shfl_xor(qa, off); qb += __shfl_xor(qb, off);
        }
        int row = rbase + lk * 4 + j;
        if (l15 == 0 && row < N_NODES) {
            int ha = wc * 2;
            s_src[row * 4 + ha]     = pa;
            s_src[row * 4 + ha + 1] = pb;
            s_dst[row * 4 + ha]     = qa;
            s_dst[row * 4 + ha + 1] = qb;
        }
    }
}

// layer-1 GEMM: A f32 converted in-register, output fp8 + scores
__device__ void gemm1_body(const float* __restrict__ A, const __hip_bfloat16* __restrict__ Bt,
                           unsigned char* __restrict__ Cq,
                           const float* __restrict__ as, const float* __restrict__ ad,
                           float* __restrict__ s_src, float* __restrict__ s_dst, int bid) {
    constexpr int NCOLS = 128;
    constexpr int CG = NCOLS / 32;
    int wid = threadIdx.x >> 6;
    int lane = threadIdx.x & 63;
    int wr = wid >> 1, wc = wid & 1;
    int l15 = lane & 15, lk = lane >> 4;

    s16x8 bfrag[CG][4];
    #pragma unroll
    for (int cg = 0; cg < CG; ++cg) {
        int col = wc * (NCOLS / 2) + cg * 16 + l15;
        #pragma unroll
        for (int ks = 0; ks < 4; ++ks)
            bfrag[cg][ks] = *(const s16x8*)&Bt[col * 128 + ks * 32 + lk * 8];
    }
    int rowblk = bid * 128;
    #pragma unroll
    for (int st = 0; st < 4; ++st) {
        int rbase = rowblk + st * 32 + wr * 16;
        int row = rbase + l15;
        bool ok = row < N_NODES;
        s16x8 afrag[4];
        #pragma unroll
        for (int ks = 0; ks < 4; ++ks) {
            if (ok) {
                float4 a0 = *(const float4*)&A[(size_t)row * 128 + ks * 32 + lk * 8];
                float4 a1 = *(const float4*)&A[(size_t)row * 128 + ks * 32 + lk * 8 + 4];
                s16x8 af;
                af[0] = f2bf(a0.x); af[1] = f2bf(a0.y); af[2] = f2bf(a0.z); af[3] = f2bf(a0.w);
                af[4] = f2bf(a1.x); af[5] = f2bf(a1.y); af[6] = f2bf(a1.z); af[7] = f2bf(a1.w);
                afrag[ks] = af;
            } else {
                afrag[ks] = (s16x8){0,0,0,0,0,0,0,0};
            }
        }
        f32x4 acc[CG];
        #pragma unroll
        for (int cg = 0; cg < CG; ++cg) acc[cg] = (f32x4){0.f, 0.f, 0.f, 0.f};
        #pragma unroll
        for (int ks = 0; ks < 4; ++ks) {
            #pragma unroll
            for (int cg = 0; cg < CG; ++cg)
                acc[cg] = __builtin_amdgcn_mfma_f32_16x16x32_bf16(afrag[ks], bfrag[cg][ks], acc[cg], 0, 0, 0);
        }
        #pragma unroll
        for (int cg = 0; cg < CG; ++cg) {
            int c = wc * (NCOLS / 2) + cg * 16 + l15;
            unsigned w01 = __builtin_amdgcn_cvt_pk_fp8_f32(acc[cg][0], acc[cg][1], 0, false);
            unsigned w23 = __builtin_amdgcn_cvt_pk_fp8_f32(acc[cg][2], acc[cg][3], 0, false);
            size_t base = (size_t)(rbase + lk * 4) * NCOLS + c;
            Cq[base]             = (unsigned char)(w01 & 0xff);
            Cq[base + NCOLS]     = (unsigned char)((w01 >> 8) & 0xff);
            Cq[base + 2 * NCOLS] = (unsigned char)(w23 & 0xff);
            Cq[base + 3 * NCOLS] = (unsigned char)((w23 >> 8) & 0xff);
        }
        score_epilogue<NCOLS>(acc, rbase, wc, l15, lk, as, ad, s_src, s_dst);
    }
}

// layer-2 GEMM: bf16 A, output fp8 + scores
template<int NCOLS>
__global__ __launch_bounds__(256) void mfma_gemm_score_kernel(const __hip_bfloat16* __restrict__ A,
                                                              const __hip_bfloat16* __restrict__ Bt,
                                                              unsigned char* __restrict__ Cq,
                                                              const float* __restrict__ as,
                                                              const float* __restrict__ ad,
                                                              float* __restrict__ s_src,
                                                              float* __restrict__ s_dst) {
    constexpr int CG = NCOLS / 32;
    int wid = threadIdx.x >> 6;
    int lane = threadIdx.x & 63;
    int wr = wid >> 1, wc = wid & 1;
    int l15 = lane & 15, lk = lane >> 4;

    s16x8 bfrag[CG][4];
    #pragma unroll
    for (int cg = 0; cg < CG; ++cg) {
        int col = wc * (NCOLS / 2) + cg * 16 + l15;
        #pragma unroll
        for (int ks = 0; ks < 4; ++ks)
            bfrag[cg][ks] = *(const s16x8*)&Bt[col * 128 + ks * 32 + lk * 8];
    }
    int rowblk = blockIdx.x * 128;
    #pragma unroll
    for (int st = 0; st < 4; ++st) {
        int rbase = rowblk + st * 32 + wr * 16;
        s16x8 afrag[4];
        #pragma unroll
        for (int ks = 0; ks < 4; ++ks)
            afrag[ks] = *(const s16x8*)&A[(size_t)(rbase + l15) * 128 + ks * 32 + lk * 8];
        f32x4 acc[CG];
        #pragma unroll
        for (int cg = 0; cg < CG; ++cg) acc[cg] = (f32x4){0.f, 0.f, 0.f, 0.f};
        #pragma unroll
        for (int ks = 0; ks < 4; ++ks) {
            #pragma unroll
            for (int cg = 0; cg < CG; ++cg)
                acc[cg] = __builtin_amdgcn_mfma_f32_16x16x32_bf16(afrag[ks], bfrag[cg][ks], acc[cg], 0, 0, 0);
        }
        #pragma unroll
        for (int cg = 0; cg < CG; ++cg) {
            int c = wc * (NCOLS / 2) + cg * 16 + l15;
            unsigned w01 = __builtin_amdgcn_cvt_pk_fp8_f32(acc[cg][0], acc[cg][1], 0, false);
            unsigned w23 = __builtin_amdgcn_cvt_pk_fp8_f32(acc[cg][2], acc[cg][3], 0, false);
            size_t base = (size_t)(rbase + lk * 4) * NCOLS + c;
            Cq[base]             = (unsigned char)(w01 & 0xff);
            Cq[base + NCOLS]     = (unsigned char)((w01 >> 8) & 0xff);
            Cq[base + 2 * NCOLS] = (unsigned char)(w23 & 0xff);
            Cq[base + 3 * NCOLS] = (unsigned char)((w23 >> 8) & 0xff);
        }
        score_epilogue<NCOLS>(acc, rbase, wc, l15, lk, as, ad, s_src, s_dst);
    }
}

// ================= mega kernels =================

__global__ __launch_bounds__(256) void k0_slice_cvtw(const int* __restrict__ ei,
                                                     int* __restrict__ cnt,
                                                     const float* __restrict__ W1,
                                                     __hip_bfloat16* __restrict__ W1t,
                                                     const float* __restrict__ W2,
                                                     __hip_bfloat16* __restrict__ W2t) {
    if (blockIdx.x < REP) { slice_count_body(ei, cnt, blockIdx.x); return; }
    cvt_w_body(W1, W1t, W2, W2t, (blockIdx.x - REP) * 256 + threadIdx.x);
}

__global__ __launch_bounds__(256) void k1_colscan_gemm1(int* __restrict__ cnt,
                                                        int* __restrict__ bsum,
                                                        const float* __restrict__ A,
                                                        const __hip_bfloat16* __restrict__ Bt,
                                                        unsigned char* __restrict__ Cq,
                                                        const float* __restrict__ as1,
                                                        const float* __restrict__ ad1,
                                                        float* __restrict__ s_src1,
                                                        float* __restrict__ s_dst1) {
    if (blockIdx.x < BUCKETS) { col_scan256_body(cnt, bsum, blockIdx.x); return; }
    gemm1_body(A, Bt, Cq, as1, ad1, s_src1, s_dst1, blockIdx.x - BUCKETS);
}

// ================= aggregation (round-11 structure, unchanged) =================

__global__ __launch_bounds__(256) void agg1_kernel(
        const unsigned char* __restrict__ h1q, const float* __restrict__ s_src,
        const float* __restrict__ s_dst, const int* __restrict__ rowptr,
        const int* __restrict__ csr, const float* __restrict__ b1,
        __hip_bfloat16* __restrict__ out1) {
    int d = blockIdx.x * 4 + (threadIdx.x >> 6);
    if (d >= N_NODES) return;
    int lane = threadIdx.x & 63;
    int c0 = lane * 2;
    int hd = lane >> 4;
    int bp = hd << 2;                                  // bpermute byte base
    int eg = (lane >> 2) & 7;                          // edge slot this lane scores
    float sdall = s_dst[d * 4 + (lane & 3)];
    f32x2 acc = {0.f, 0.f};
    float z = 0.f;
    int beg = __builtin_amdgcn_readfirstlane(rowptr[d]);
    int end = __builtin_amdgcn_readfirstlane(rowptr[d + 1]);
    for (int j = beg; j < end; j += 8) {
        int cnt = end - j;
        int se = csr[min(j + eg, end - 1)];
        float ee = s_src[(size_t)se * 4 + (lane & 3)] + sdall;
        ee = fmaxf(ee, NEG_SLOPE * ee);
        float qv = (eg < cnt) ? __expf(ee) : 0.f;
        int qbits = __float_as_int(qv);
        #pragma unroll
        for (int t = 0; t < 8; ++t) {
            float q = __int_as_float(__builtin_amdgcn_ds_bpermute(bp + t * 16, qbits));
            int s = __builtin_amdgcn_readfirstlane(csr[min(j + t, end - 1)]);
            const unsigned char* row = h1q + (size_t)s * 128;
            unsigned u = *(const unsigned short*)&row[c0];
            f32x2 v = __builtin_amdgcn_cvt_pk_f32_fp8(u, false);
            f32x2 qq = {q, q};
            acc += qq * v;
            z += q;
        }
    }
    float invz = 1.0f / z;
    float vx = acc.x * invz + b1[c0];
    float vy = acc.y * invz + b1[c0 + 1];
    vx = vx > 0.f ? vx : __expf(vx) - 1.0f;   // ELU
    vy = vy > 0.f ? vy : __expf(vy) - 1.0f;
    __hip_bfloat162 o;
    o.x = __float2bfloat16(vx);
    o.y = __float2bfloat16(vy);
    *(__hip_bfloat162*)&out1[(size_t)d * 128 + c0] = o;
}

__global__ __launch_bounds__(256) void agg2_kernel(
        const unsigned char* __restrict__ h2q, const float* __restrict__ s_src,
        const float* __restrict__ s_dst, const int* __restrict__ rowptr,
        const int* __restrict__ csr, const float* __restrict__ b2,
        float* __restrict__ out) {
    int d = blockIdx.x * 4 + (threadIdx.x >> 6);
    if (d >= N_NODES) return;
    int lane = threadIdx.x & 63;
    int ll = lane < 40 ? lane : 39;
    int hd = ll / 10;
    int bp = hd << 2;
    int eg = (lane >> 2) & 7;
    int voff = ll * 4;                         // byte offset within 160-B row
    float sdall = s_dst[d * 4 + (lane & 3)];
    f32x2 acc01 = {0.f, 0.f}, acc23 = {0.f, 0.f};
    float z = 0.f;
    int beg = __builtin_amdgcn_readfirstlane(rowptr[d]);
    int end = __builtin_amdgcn_readfirstlane(rowptr[d + 1]);
    for (int j = beg; j < end; j += 8) {
        int cnt = end - j;
        int se = csr[min(j + eg, end - 1)];
        float ee = s_src[(size_t)se * 4 + (lane & 3)] + sdall;
        ee = fmaxf(ee, NEG_SLOPE * ee);
        float qv = (eg < cnt) ? __expf(ee) : 0.f;
        int qbits = __float_as_int(qv);
        #pragma unroll
        for (int t = 0; t < 8; ++t) {
            float q = __int_as_float(__builtin_amdgcn_ds_bpermute(bp + t * 16, qbits));
            int s = __builtin_amdgcn_readfirstlane(csr[min(j + t, end - 1)]);
            const unsigned char* row = h2q + (size_t)s * 160;
            unsigned u = *(const unsigned*)&row[voff];
            f32x2 v01 = __builtin_amdgcn_cvt_pk_f32_fp8(u, false);
            f32x2 v23 = __builtin_amdgcn_cvt_pk_f32_fp8(u, true);
            f32x2 qq = {q, q};
            acc01 += qq * v01;
            acc23 += qq * v23;
            z += q;
        }
    }
    float invz = 1.0f / z;
    float rx = acc01.x * invz, ry = acc01.y * invz;
    float rz = acc23.x * invz, rw = acc23.y * invz;
    float sx = rx + __shfl(rx, lane + 10) + __shfl(rx, lane + 20) + __shfl(rx, lane + 30);
    float sy = ry + __shfl(ry, lane + 10) + __shfl(ry, lane + 20) + __shfl(ry, lane + 30);
    float sz = rz + __shfl(rz, lane + 10) + __shfl(rz, lane + 20) + __shfl(rz, lane + 30);
    float sw = rw + __shfl(rw, lane + 10) + __shfl(rw, lane + 20) + __shfl(rw, lane + 30);
    int lc = lane < 10 ? lane : 9;
    float4 bb = *(const float4*)&b2[lc * 4];
    bool own = lane < 10;
    float vx = own ? sx * 0.25f + bb.x : -1e30f;
    float vy = own ? sy * 0.25f + bb.y : -1e30f;
    float vz = own ? sz * 0.25f + bb.z : -1e30f;
    float vw = own ? sw * 0.25f + bb.w : -1e30f;
    float m = fmaxf(fmaxf(vx, vy), fmaxf(vz, vw));
    #pragma unroll
    for (int off = 1; off < 16; off <<= 1) m = fmaxf(m, __shfl_xor(m, off));
    float ssum = 0.f;
    if (own) {
        ssum = __expf(vx - m) + __expf(vy - m) + __expf(vz - m) + __expf(vw - m);
    }
    #pragma unroll
    for (int off = 1; off < 16; off <<= 1) ssum += __shfl_xor(ssum, off);
    float lse = m + __logf(ssum);
    if (own) {
        float4 o = {vx - lse, vy - lse, vz - lse, vw - lse};
        *(float4*)&out[(size_t)d * 40 + lane * 4] = o;
    }
}

// ================= launch =================

extern "C" void kernel_launch(void* const* d_in, const int* in_sizes, int n_in,
                              void* d_out, int out_size, void* d_ws, size_t ws_size,
                              hipStream_t stream) {
    const float* x   = (const float*)d_in[0];
    const int*   ei  = (const int*)d_in[1];
    const float* W1  = (const float*)d_in[2];
    const float* as1 = (const float*)d_in[3];
    const float* ad1 = (const float*)d_in[4];
    const float* b1  = (const float*)d_in[5];
    const float* W2  = (const float*)d_in[6];
    const float* as2 = (const float*)d_in[7];
    const float* ad2 = (const float*)d_in[8];
    const float* b2  = (const float*)d_in[9];
    float* out = (float*)d_out;

    char* ws = (char*)d_ws;
    size_t off = 0;
    auto alloc = [&](size_t bytes) {
        void* p = ws + off;
        off += (bytes + 255) & ~(size_t)255;
        return p;
    };
    unsigned char*  h1q   = (unsigned char*)alloc((size_t)M_PAD * 128);
    unsigned char*  h2q   = (unsigned char*)alloc((size_t)M_PAD * 160);
    __hip_bfloat16* out1b = (__hip_bfloat16*)alloc((size_t)M_PAD * 128 * 2);
    __hip_bfloat16* W1t   = (__hip_bfloat16*)alloc((size_t)128 * 128 * 2);
    __hip_bfloat16* W2t   = (__hip_bfloat16*)alloc((size_t)160 * 128 * 2);
    float* s_src1  = (float*)alloc((size_t)N_NODES * 4 * 4);
    float* s_dst1  = (float*)alloc((size_t)N_NODES * 4 * 4);
    float* s_src2  = (float*)alloc((size_t)N_NODES * 4 * 4);
    float* s_dst2  = (float*)alloc((size_t)N_NODES * 4 * 4);
    int*   tmp     = (int*)alloc((size_t)E_TOT * 4);
    int*   rowptr  = (int*)alloc((size_t)(N_NODES + 1) * 4);
    int*   csr     = (int*)alloc((size_t)(E_TOT + 8) * 4);   // +8 pad
    int*   cnt     = (int*)alloc((size_t)REP * BUCKETS * 4);
    int*   bsum    = (int*)alloc((size_t)BUCKETS * 4);
    int*   boff    = (int*)alloc((size_t)(BUCKETS + 1) * 4);

    // K0: slice-count (CSR) || weight conversion
    k0_slice_cvtw<<<REP + CVTW_BLOCKS, 256, 0, stream>>>(ei, cnt, W1, W1t, W2, W2t);
    // K1: column scan (CSR) || GEMM layer 1 (f32 x -> fp8 h1q) + fused score1
    k1_colscan_gemm1<<<BUCKETS + GB1, 256, 0, stream>>>(cnt, bsum, x, W1t, h1q,
                                                        as1, ad1, s_src1, s_dst1);
    // CSR finish
    bucket_scan_kernel<<<1, 1024, 0, stream>>>(bsum, boff);
    bucket_scatter_kernel<<<REP, 256, 0, stream>>>(ei, cnt, boff, tmp);
    bucket_build_kernel<<<BUCKETS, 256, 0, stream>>>(tmp, boff, rowptr, csr);

    // layer 1 aggregation
    agg1_kernel<<<(N_NODES + 3) / 4, 256, 0, stream>>>(h1q, s_src1, s_dst1, rowptr, csr, b1, out1b);

    // layer 2: GEMM + fused score2, then aggregation
    mfma_gemm_score_kernel<160><<<GB1, 256, 0, stream>>>(out1b, W2t, h2q,
                                                         as2, ad2, s_src2, s_dst2);
    agg2_kernel<<<(N_NODES + 3) / 4, 256, 0, stream>>>(h2q, s_src2, s_dst2, rowptr, csr, b2, out);
}

// Round 18
// 232.058 us; speedup vs baseline: 1.0642x; 1.0123x over previous
//
#include <hip/hip_runtime.h>
#include <hip/hip_bf16.h>

#define N_NODES 100000
#define M_PAD   100096            // 782 * 128, padded row count for MFMA GEMM
#define N_EDGES 1600000
#define E_TOT   (N_EDGES + N_NODES)   // + self loops
#define NEG_SLOPE 0.2f

#define G_NODES 128                                  // nodes per bucket (pow2)
#define BUCKETS ((N_NODES + G_NODES - 1) / G_NODES)  // 782
#define REP 512                                      // slices
#define SLICE ((E_TOT + REP - 1) / REP)              // 3321 edges per slice
#define GB1 (M_PAD / 128)                            // 782 gemm blocks
#define CVTW_ELEMS (128 * 128 + 128 * 160)
#define CVTW_BLOCKS ((CVTW_ELEMS + 255) / 256)

typedef __attribute__((ext_vector_type(8))) short s16x8;
typedef __attribute__((ext_vector_type(4))) float f32x4;
typedef __attribute__((ext_vector_type(2))) float f32x2;

__device__ __forceinline__ float lo16(unsigned u) { return __uint_as_float(u << 16); }
__device__ __forceinline__ float hi16(unsigned u) { return __uint_as_float(u & 0xffff0000u); }

__device__ __forceinline__ short f2bf(float f) {
    __hip_bfloat16 b = __float2bfloat16(f);
    return *(short*)&b;
}

// ================= CSR build bodies =================

__device__ void slice_count_body(const int* __restrict__ ei, int* __restrict__ cnt, int r) {
    __shared__ int h[BUCKETS];
    for (int i = threadIdx.x; i < BUCKETS; i += 256) h[i] = 0;
    __syncthreads();
    int lo = r * SLICE, hi = min(lo + SLICE, E_TOT);
    for (int e = lo + threadIdx.x; e < hi; e += 256) {
        int d = (e < N_EDGES) ? ei[N_EDGES + e] : e - N_EDGES;
        atomicAdd(&h[d >> 7], 1);
    }
    __syncthreads();
    for (int i = threadIdx.x; i < BUCKETS; i += 256)
        cnt[(size_t)r * BUCKETS + i] = h[i];
}

// 256 threads, 2 slice-rows per thread: exclusive scan down bucket b's column
__global__ __launch_bounds__(256) void col_scan_kernel(int* __restrict__ cnt,
                                                       int* __restrict__ bsum) {
    __shared__ int lds[256];
    int b = blockIdx.x;
    int tid = threadIdx.x;
    int v0 = cnt[(size_t)(2 * tid) * BUCKETS + b];
    int v1 = cnt[(size_t)(2 * tid + 1) * BUCKETS + b];
    int s = v0 + v1;
    lds[tid] = s;
    __syncthreads();
    for (int off = 1; off < 256; off <<= 1) {
        int t = (tid >= off) ? lds[tid - off] : 0;
        __syncthreads();
        lds[tid] += t;
        __syncthreads();
    }
    int excl = lds[tid] - s;
    cnt[(size_t)(2 * tid) * BUCKETS + b]     = excl;
    cnt[(size_t)(2 * tid + 1) * BUCKETS + b] = excl + v0;
    if (tid == 255) bsum[b] = lds[255];
}

__global__ __launch_bounds__(1024) void bucket_scan_kernel(const int* __restrict__ bsum,
                                                           int* __restrict__ boff) {
    __shared__ int lds[1024];
    int tid = threadIdx.x;
    int v = (tid < BUCKETS) ? bsum[tid] : 0;
    lds[tid] = v;
    __syncthreads();
    for (int off = 1; off < 1024; off <<= 1) {
        int t = (tid >= off) ? lds[tid - off] : 0;
        __syncthreads();
        lds[tid] += t;
        __syncthreads();
    }
    if (tid < BUCKETS) boff[tid] = lds[tid] - v;
    if (tid == 0) boff[BUCKETS] = E_TOT;
}

__device__ void bucket_scatter_body(const int* __restrict__ ei,
                                    const int* __restrict__ colx,
                                    const int* __restrict__ boff,
                                    int* __restrict__ tmp, int r) {
    __shared__ int lcur[BUCKETS];
    for (int i = threadIdx.x; i < BUCKETS; i += 256)
        lcur[i] = boff[i] + colx[(size_t)r * BUCKETS + i];
    __syncthreads();
    int lo = r * SLICE, hi = min(lo + SLICE, E_TOT);
    for (int e = lo + threadIdx.x; e < hi; e += 256) {
        int s, d;
        if (e < N_EDGES) { s = ei[e]; d = ei[N_EDGES + e]; }
        else             { s = d = e - N_EDGES; }
        int pos = atomicAdd(&lcur[d >> 7], 1);
        tmp[pos] = (s << 7) | (d & (G_NODES - 1));
    }
}

__global__ __launch_bounds__(256) void bucket_build_kernel(const int* __restrict__ tmp,
                                                           const int* __restrict__ boff,
                                                           int* __restrict__ rowptr,
                                                           int* __restrict__ csr) {
    __shared__ int hcnt[G_NODES];
    __shared__ int hoff[G_NODES];
    int b = blockIdx.x;
    int base = boff[b], cnt = boff[b + 1] - base;
    int tid = threadIdx.x;
    if (tid < G_NODES) hcnt[tid] = 0;
    __syncthreads();
    for (int i = tid; i < cnt; i += 256)
        atomicAdd(&hcnt[tmp[base + i] & (G_NODES - 1)], 1);
    __syncthreads();
    if (tid < G_NODES) hoff[tid] = hcnt[tid];
    __syncthreads();
    for (int off = 1; off < G_NODES; off <<= 1) {
        int t = (tid < G_NODES && tid >= off) ? hoff[tid - off] : 0;
        __syncthreads();
        if (tid < G_NODES) hoff[tid] += t;
        __syncthreads();
    }
    if (tid < G_NODES) {
        int excl = hoff[tid] - hcnt[tid];
        int node = b * G_NODES + tid;
        if (node < N_NODES) rowptr[node] = base + excl;
        hcnt[tid] = excl;       // reuse as cursor
    }
    __syncthreads();
    for (int i = tid; i < cnt; i += 256) {
        int v = tmp[base + i];
        int pos = base + atomicAdd(&hcnt[v & (G_NODES - 1)], 1);
        csr[pos] = v >> 7;
    }
    if (b == 0 && tid < 8) csr[E_TOT + tid] = 0;
    if (b == 0 && tid == 0) rowptr[N_NODES] = E_TOT;
}

// ================= weights =================

__device__ void cvt_w_body(const float* __restrict__ W1, __hip_bfloat16* __restrict__ W1t,
                           const float* __restrict__ W2, __hip_bfloat16* __restrict__ W2t,
                           int idx) {
    if (idx < 128 * 128) {
        int k = idx >> 7, n = idx & 127;
        W1t[n * 128 + k] = __float2bfloat16(W1[idx]);
    } else if (idx < CVTW_ELEMS) {
        int i = idx - 128 * 128;
        int k = i / 160, n = i - k * 160;
        W2t[n * 128 + k] = __float2bfloat16(W2[i]);
    }
}

// ================= fused GEMM + score epilogue =================

template<int NCOLS>
__device__ __forceinline__ void score_epilogue(const f32x4* acc, int rbase, int wc,
                                               int l15, int lk,
                                               const float* __restrict__ as,
                                               const float* __restrict__ ad,
                                               float* __restrict__ s_src,
                                               float* __restrict__ s_dst) {
    constexpr int CG = NCOLS / 32;
    constexpr int HEADW = NCOLS / 4;
    #pragma unroll
    for (int j = 0; j < 4; ++j) {
        float pa = 0.f, pb = 0.f, qa = 0.f, qb = 0.f;
        #pragma unroll
        for (int cg = 0; cg < CG; ++cg) {
            int c = wc * (NCOLS / 2) + cg * 16 + l15;
            float v = acc[cg][j];
            float ws = as[c], wd = ad[c];
            if (c >= (wc * 2 + 1) * HEADW) { pb += v * ws; qb += v * wd; }
            else                           { pa += v * ws; qa += v * wd; }
        }
        #pragma unroll
        for (int off = 1; off < 16; off <<= 1) {
            pa += __shfl_xor(pa, off); pb += __shfl_xor(pb, off);
            qa += __shfl_xor(qa, off); qb += __shfl_xor(qb, off);
        }
        int row = rbase + lk * 4 + j;
        if (l15 == 0 && row < N_NODES) {
            int ha = wc * 2;
            s_src[row * 4 + ha]     = pa;
            s_src[row * 4 + ha + 1] = pb;
            s_dst[row * 4 + ha]     = qa;
            s_dst[row * 4 + ha + 1] = qb;
        }
    }
}

// layer-1 GEMM: A f32 converted in-register, output fp8 + scores
__device__ void gemm1_body(const float* __restrict__ A, const __hip_bfloat16* __restrict__ Bt,
                           unsigned char* __restrict__ Cq,
                           const float* __restrict__ as, const float* __restrict__ ad,
                           float* __restrict__ s_src, float* __restrict__ s_dst, int bid) {
    constexpr int NCOLS = 128;
    constexpr int CG = NCOLS / 32;
    int wid = threadIdx.x >> 6;
    int lane = threadIdx.x & 63;
    int wr = wid >> 1, wc = wid & 1;
    int l15 = lane & 15, lk = lane >> 4;

    s16x8 bfrag[CG][4];
    #pragma unroll
    for (int cg = 0; cg < CG; ++cg) {
        int col = wc * (NCOLS / 2) + cg * 16 + l15;
        #pragma unroll
        for (int ks = 0; ks < 4; ++ks)
            bfrag[cg][ks] = *(const s16x8*)&Bt[col * 128 + ks * 32 + lk * 8];
    }
    int rowblk = bid * 128;
    #pragma unroll
    for (int st = 0; st < 4; ++st) {
        int rbase = rowblk + st * 32 + wr * 16;
        int row = rbase + l15;
        bool ok = row < N_NODES;
        s16x8 afrag[4];
        #pragma unroll
        for (int ks = 0; ks < 4; ++ks) {
            if (ok) {
                float4 a0 = *(const float4*)&A[(size_t)row * 128 + ks * 32 + lk * 8];
                float4 a1 = *(const float4*)&A[(size_t)row * 128 + ks * 32 + lk * 8 + 4];
                s16x8 af;
                af[0] = f2bf(a0.x); af[1] = f2bf(a0.y); af[2] = f2bf(a0.z); af[3] = f2bf(a0.w);
                af[4] = f2bf(a1.x); af[5] = f2bf(a1.y); af[6] = f2bf(a1.z); af[7] = f2bf(a1.w);
                afrag[ks] = af;
            } else {
                afrag[ks] = (s16x8){0,0,0,0,0,0,0,0};
            }
        }
        f32x4 acc[CG];
        #pragma unroll
        for (int cg = 0; cg < CG; ++cg) acc[cg] = (f32x4){0.f, 0.f, 0.f, 0.f};
        #pragma unroll
        for (int ks = 0; ks < 4; ++ks) {
            #pragma unroll
            for (int cg = 0; cg < CG; ++cg)
                acc[cg] = __builtin_amdgcn_mfma_f32_16x16x32_bf16(afrag[ks], bfrag[cg][ks], acc[cg], 0, 0, 0);
        }
        #pragma unroll
        for (int cg = 0; cg < CG; ++cg) {
            int c = wc * (NCOLS / 2) + cg * 16 + l15;
            unsigned w01 = __builtin_amdgcn_cvt_pk_fp8_f32(acc[cg][0], acc[cg][1], 0, false);
            unsigned w23 = __builtin_amdgcn_cvt_pk_fp8_f32(acc[cg][2], acc[cg][3], 0, false);
            size_t base = (size_t)(rbase + lk * 4) * NCOLS + c;
            Cq[base]             = (unsigned char)(w01 & 0xff);
            Cq[base + NCOLS]     = (unsigned char)((w01 >> 8) & 0xff);
            Cq[base + 2 * NCOLS] = (unsigned char)(w23 & 0xff);
            Cq[base + 3 * NCOLS] = (unsigned char)((w23 >> 8) & 0xff);
        }
        score_epilogue<NCOLS>(acc, rbase, wc, l15, lk, as, ad, s_src, s_dst);
    }
}

// layer-2 GEMM: bf16 A, output fp8 + scores
template<int NCOLS>
__global__ __launch_bounds__(256) void mfma_gemm_score_kernel(const __hip_bfloat16* __restrict__ A,
                                                              const __hip_bfloat16* __restrict__ Bt,
                                                              unsigned char* __restrict__ Cq,
                                                              const float* __restrict__ as,
                                                              const float* __restrict__ ad,
                                                              float* __restrict__ s_src,
                                                              float* __restrict__ s_dst) {
    constexpr int CG = NCOLS / 32;
    int wid = threadIdx.x >> 6;
    int lane = threadIdx.x & 63;
    int wr = wid >> 1, wc = wid & 1;
    int l15 = lane & 15, lk = lane >> 4;

    s16x8 bfrag[CG][4];
    #pragma unroll
    for (int cg = 0; cg < CG; ++cg) {
        int col = wc * (NCOLS / 2) + cg * 16 + l15;
        #pragma unroll
        for (int ks = 0; ks < 4; ++ks)
            bfrag[cg][ks] = *(const s16x8*)&Bt[col * 128 + ks * 32 + lk * 8];
    }
    int rowblk = blockIdx.x * 128;
    #pragma unroll
    for (int st = 0; st < 4; ++st) {
        int rbase = rowblk + st * 32 + wr * 16;
        s16x8 afrag[4];
        #pragma unroll
        for (int ks = 0; ks < 4; ++ks)
            afrag[ks] = *(const s16x8*)&A[(size_t)(rbase + l15) * 128 + ks * 32 + lk * 8];
        f32x4 acc[CG];
        #pragma unroll
        for (int cg = 0; cg < CG; ++cg) acc[cg] = (f32x4){0.f, 0.f, 0.f, 0.f};
        #pragma unroll
        for (int ks = 0; ks < 4; ++ks) {
            #pragma unroll
            for (int cg = 0; cg < CG; ++cg)
                acc[cg] = __builtin_amdgcn_mfma_f32_16x16x32_bf16(afrag[ks], bfrag[cg][ks], acc[cg], 0, 0, 0);
        }
        #pragma unroll
        for (int cg = 0; cg < CG; ++cg) {
            int c = wc * (NCOLS / 2) + cg * 16 + l15;
            unsigned w01 = __builtin_amdgcn_cvt_pk_fp8_f32(acc[cg][0], acc[cg][1], 0, false);
            unsigned w23 = __builtin_amdgcn_cvt_pk_fp8_f32(acc[cg][2], acc[cg][3], 0, false);
            size_t base = (size_t)(rbase + lk * 4) * NCOLS + c;
            Cq[base]             = (unsigned char)(w01 & 0xff);
            Cq[base + NCOLS]     = (unsigned char)((w01 >> 8) & 0xff);
            Cq[base + 2 * NCOLS] = (unsigned char)(w23 & 0xff);
            Cq[base + 3 * NCOLS] = (unsigned char)((w23 >> 8) & 0xff);
        }
        score_epilogue<NCOLS>(acc, rbase, wc, l15, lk, as, ad, s_src, s_dst);
    }
}

// ================= mega kernels =================

__global__ __launch_bounds__(256) void k0_slice_cvtw(const int* __restrict__ ei,
                                                     int* __restrict__ cnt,
                                                     const float* __restrict__ W1,
                                                     __hip_bfloat16* __restrict__ W1t,
                                                     const float* __restrict__ W2,
                                                     __hip_bfloat16* __restrict__ W2t) {
    if (blockIdx.x < REP) { slice_count_body(ei, cnt, blockIdx.x); return; }
    cvt_w_body(W1, W1t, W2, W2t, (blockIdx.x - REP) * 256 + threadIdx.x);
}

// scatter (CSR) || GEMM1 + fused score1
__global__ __launch_bounds__(256) void kS_scatter_gemm1(const int* __restrict__ ei,
                                                        const int* __restrict__ colx,
                                                        const int* __restrict__ boff,
                                                        int* __restrict__ tmp,
                                                        const float* __restrict__ A,
                                                        const __hip_bfloat16* __restrict__ Bt,
                                                        unsigned char* __restrict__ Cq,
                                                        const float* __restrict__ as1,
                                                        const float* __restrict__ ad1,
                                                        float* __restrict__ s_src1,
                                                        float* __restrict__ s_dst1) {
    if (blockIdx.x < REP) { bucket_scatter_body(ei, colx, boff, tmp, blockIdx.x); return; }
    gemm1_body(A, Bt, Cq, as1, ad1, s_src1, s_dst1, blockIdx.x - REP);
}

// ================= aggregation (round-11 structure, unchanged) =================

__global__ __launch_bounds__(256) void agg1_kernel(
        const unsigned char* __restrict__ h1q, const float* __restrict__ s_src,
        const float* __restrict__ s_dst, const int* __restrict__ rowptr,
        const int* __restrict__ csr, const float* __restrict__ b1,
        __hip_bfloat16* __restrict__ out1) {
    int d = blockIdx.x * 4 + (threadIdx.x >> 6);
    if (d >= N_NODES) return;
    int lane = threadIdx.x & 63;
    int c0 = lane * 2;
    int hd = lane >> 4;
    int bp = hd << 2;                                  // bpermute byte base
    int eg = (lane >> 2) & 7;                          // edge slot this lane scores
    float sdall = s_dst[d * 4 + (lane & 3)];
    f32x2 acc = {0.f, 0.f};
    float z = 0.f;
    int beg = __builtin_amdgcn_readfirstlane(rowptr[d]);
    int end = __builtin_amdgcn_readfirstlane(rowptr[d + 1]);
    for (int j = beg; j < end; j += 8) {
        int cnt = end - j;
        int se = csr[min(j + eg, end - 1)];
        float ee = s_src[(size_t)se * 4 + (lane & 3)] + sdall;
        ee = fmaxf(ee, NEG_SLOPE * ee);
        float qv = (eg < cnt) ? __expf(ee) : 0.f;
        int qbits = __float_as_int(qv);
        #pragma unroll
        for (int t = 0; t < 8; ++t) {
            float q = __int_as_float(__builtin_amdgcn_ds_bpermute(bp + t * 16, qbits));
            int s = __builtin_amdgcn_readfirstlane(csr[min(j + t, end - 1)]);
            const unsigned char* row = h1q + (size_t)s * 128;
            unsigned u = *(const unsigned short*)&row[c0];
            f32x2 v = __builtin_amdgcn_cvt_pk_f32_fp8(u, false);
            f32x2 qq = {q, q};
            acc += qq * v;
            z += q;
        }
    }
    float invz = 1.0f / z;
    float vx = acc.x * invz + b1[c0];
    float vy = acc.y * invz + b1[c0 + 1];
    vx = vx > 0.f ? vx : __expf(vx) - 1.0f;   // ELU
    vy = vy > 0.f ? vy : __expf(vy) - 1.0f;
    __hip_bfloat162 o;
    o.x = __float2bfloat16(vx);
    o.y = __float2bfloat16(vy);
    *(__hip_bfloat162*)&out1[(size_t)d * 128 + c0] = o;
}

__global__ __launch_bounds__(256) void agg2_kernel(
        const unsigned char* __restrict__ h2q, const float* __restrict__ s_src,
        const float* __restrict__ s_dst, const int* __restrict__ rowptr,
        const int* __restrict__ csr, const float* __restrict__ b2,
        float* __restrict__ out) {
    int d = blockIdx.x * 4 + (threadIdx.x >> 6);
    if (d >= N_NODES) return;
    int lane = threadIdx.x & 63;
    int ll = lane < 40 ? lane : 39;
    int hd = ll / 10;
    int bp = hd << 2;
    int eg = (lane >> 2) & 7;
    int voff = ll * 4;                         // byte offset within 160-B row
    float sdall = s_dst[d * 4 + (lane & 3)];
    f32x2 acc01 = {0.f, 0.f}, acc23 = {0.f, 0.f};
    float z = 0.f;
    int beg = __builtin_amdgcn_readfirstlane(rowptr[d]);
    int end = __builtin_amdgcn_readfirstlane(rowptr[d + 1]);
    for (int j = beg; j < end; j += 8) {
        int cnt = end - j;
        int se = csr[min(j + eg, end - 1)];
        float ee = s_src[(size_t)se * 4 + (lane & 3)] + sdall;
        ee = fmaxf(ee, NEG_SLOPE * ee);
        float qv = (eg < cnt) ? __expf(ee) : 0.f;
        int qbits = __float_as_int(qv);
        #pragma unroll
        for (int t = 0; t < 8; ++t) {
            float q = __int_as_float(__builtin_amdgcn_ds_bpermute(bp + t * 16, qbits));
            int s = __builtin_amdgcn_readfirstlane(csr[min(j + t, end - 1)]);
            const unsigned char* row = h2q + (size_t)s * 160;
            unsigned u = *(const unsigned*)&row[voff];
            f32x2 v01 = __builtin_amdgcn_cvt_pk_f32_fp8(u, false);
            f32x2 v23 = __builtin_amdgcn_cvt_pk_f32_fp8(u, true);
            f32x2 qq = {q, q};
            acc01 += qq * v01;
            acc23 += qq * v23;
            z += q;
        }
    }
    float invz = 1.0f / z;
    float rx = acc01.x * invz, ry = acc01.y * invz;
    float rz = acc23.x * invz, rw = acc23.y * invz;
    float sx = rx + __shfl(rx, lane + 10) + __shfl(rx, lane + 20) + __shfl(rx, lane + 30);
    float sy = ry + __shfl(ry, lane + 10) + __shfl(ry, lane + 20) + __shfl(ry, lane + 30);
    float sz = rz + __shfl(rz, lane + 10) + __shfl(rz, lane + 20) + __shfl(rz, lane + 30);
    float sw = rw + __shfl(rw, lane + 10) + __shfl(rw, lane + 20) + __shfl(rw, lane + 30);
    int lc = lane < 10 ? lane : 9;
    float4 bb = *(const float4*)&b2[lc * 4];
    bool own = lane < 10;
    float vx = own ? sx * 0.25f + bb.x : -1e30f;
    float vy = own ? sy * 0.25f + bb.y : -1e30f;
    float vz = own ? sz * 0.25f + bb.z : -1e30f;
    float vw = own ? sw * 0.25f + bb.w : -1e30f;
    float m = fmaxf(fmaxf(vx, vy), fmaxf(vz, vw));
    #pragma unroll
    for (int off = 1; off < 16; off <<= 1) m = fmaxf(m, __shfl_xor(m, off));
    float ssum = 0.f;
    if (own) {
        ssum = __expf(vx - m) + __expf(vy - m) + __expf(vz - m) + __expf(vw - m);
    }
    #pragma unroll
    for (int off = 1; off < 16; off <<= 1) ssum += __shfl_xor(ssum, off);
    float lse = m + __logf(ssum);
    if (own) {
        float4 o = {vx - lse, vy - lse, vz - lse, vw - lse};
        *(float4*)&out[(size_t)d * 40 + lane * 4] = o;
    }
}

// ================= launch =================

extern "C" void kernel_launch(void* const* d_in, const int* in_sizes, int n_in,
                              void* d_out, int out_size, void* d_ws, size_t ws_size,
                              hipStream_t stream) {
    const float* x   = (const float*)d_in[0];
    const int*   ei  = (const int*)d_in[1];
    const float* W1  = (const float*)d_in[2];
    const float* as1 = (const float*)d_in[3];
    const float* ad1 = (const float*)d_in[4];
    const float* b1  = (const float*)d_in[5];
    const float* W2  = (const float*)d_in[6];
    const float* as2 = (const float*)d_in[7];
    const float* ad2 = (const float*)d_in[8];
    const float* b2  = (const float*)d_in[9];
    float* out = (float*)d_out;

    char* ws = (char*)d_ws;
    size_t off = 0;
    auto alloc = [&](size_t bytes) {
        void* p = ws + off;
        off += (bytes + 255) & ~(size_t)255;
        return p;
    };
    unsigned char*  h1q   = (unsigned char*)alloc((size_t)M_PAD * 128);
    unsigned char*  h2q   = (unsigned char*)alloc((size_t)M_PAD * 160);
    __hip_bfloat16* out1b = (__hip_bfloat16*)alloc((size_t)M_PAD * 128 * 2);
    __hip_bfloat16* W1t   = (__hip_bfloat16*)alloc((size_t)128 * 128 * 2);
    __hip_bfloat16* W2t   = (__hip_bfloat16*)alloc((size_t)160 * 128 * 2);
    float* s_src1  = (float*)alloc((size_t)N_NODES * 4 * 4);
    float* s_dst1  = (float*)alloc((size_t)N_NODES * 4 * 4);
    float* s_src2  = (float*)alloc((size_t)N_NODES * 4 * 4);
    float* s_dst2  = (float*)alloc((size_t)N_NODES * 4 * 4);
    int*   tmp     = (int*)alloc((size_t)E_TOT * 4);
    int*   rowptr  = (int*)alloc((size_t)(N_NODES + 1) * 4);
    int*   csr     = (int*)alloc((size_t)(E_TOT + 8) * 4);   // +8 pad
    int*   cnt     = (int*)alloc((size_t)REP * BUCKETS * 4);
    int*   bsum    = (int*)alloc((size_t)BUCKETS * 4);
    int*   boff    = (int*)alloc((size_t)(BUCKETS + 1) * 4);

    // K0: slice-count (CSR) || weight conversion
    k0_slice_cvtw<<<REP + CVTW_BLOCKS, 256, 0, stream>>>(ei, cnt, W1, W1t, W2, W2t);
    // column scan + bucket scan (CSR offsets)
    col_scan_kernel<<<BUCKETS, 256, 0, stream>>>(cnt, bsum);
    bucket_scan_kernel<<<1, 1024, 0, stream>>>(bsum, boff);
    // KS: scatter (CSR) || GEMM layer 1 (f32 x -> fp8 h1q) + fused score1
    kS_scatter_gemm1<<<REP + GB1, 256, 0, stream>>>(ei, cnt, boff, tmp,
                                                    x, W1t, h1q, as1, ad1, s_src1, s_dst1);
    // CSR finish
    bucket_build_kernel<<<BUCKETS, 256, 0, stream>>>(tmp, boff, rowptr, csr);

    // layer 1 aggregation
    agg1_kernel<<<(N_NODES + 3) / 4, 256, 0, stream>>>(h1q, s_src1, s_dst1, rowptr, csr, b1, out1b);

    // layer 2: GEMM + fused score2, then aggregation
    mfma_gemm_score_kernel<160><<<GB1, 256, 0, stream>>>(out1b, W2t, h2q,
                                                         as2, ad2, s_src2, s_dst2);
    agg2_kernel<<<(N_NODES + 3) / 4, 256, 0, stream>>>(h2q, s_src2, s_dst2, rowptr, csr, b2, out);
}